// Round 15
// baseline (221.654 us; speedup 1.0000x reference)
//
#include <hip/hip_runtime.h>
#include <hip/hip_bf16.h>
#include <stdint.h>

#define KDIM    256
#define NWORDS  1564         // sign words per column (= gemm grid: 64-row stripes)
#define NW      1563         // crossing words (ceil(99999/64))
#define AT_ROWS 100096       // padded rows in At
#define AT_TSTRIDE ((size_t)AT_ROWS * 64)   // bytes per K-tile plane: 6406144

typedef float  f32x4  __attribute__((ext_vector_type(4)));
typedef __bf16 bf16x8 __attribute__((ext_vector_type(8)));
typedef __bf16 bf16x4 __attribute__((ext_vector_type(4)));

// ---------- K0: build W, tile-major ----------
// Wt[t][j][32 bf16]: K-tile t, row j. A (t,j) slice is 64B; a B-fragment
// wave-load (16 cols x 64B) is 1KB fully contiguous.
__global__ void build_w(const float* __restrict__ theta,
                        const float* __restrict__ noise,
                        __bf16* __restrict__ Wt) {
    int idx = blockIdx.x * 256 + threadIdx.x;   // 0..262143
    int j = idx >> 9;
    int d = idx & 511;
    float v;
    if (j < KDIM) v = theta[j * 512 + d];
    else          v = theta[(j - KDIM) * 512 + d] + 0.01f * noise[(j - KDIM) * 512 + d];
    Wt[((d >> 5) * 512 + j) * 32 + (d & 31)] = (__bf16)v;
}

// ---------- K0b: cast basis f32 -> bf16, K-tile-major At[t][row][32] ----------
// Pure streaming: block = 64 rows; reads 128KB linear f32, writes 16 x 4KB
// linear bf16 chunks. Separate dispatch = the A-stream runs at clean rates,
// never mixed with MFMA machinery.
__global__ void __launch_bounds__(512)
cast_a(const float* __restrict__ basis, __bf16* __restrict__ At) {
    const int tid = threadIdx.x;
    const int bm  = blockIdx.x;          // 0..1563
    const int rl  = tid >> 3;            // 0..63
    const int oct = tid & 7;             // 16B f32 slice within a 128B tile-row
    int rsrc = bm * 64 + rl; if (rsrc > 99999) rsrc = 99999;   // tail clamp
    const float* src = basis + (size_t)rsrc * 512 + oct * 4;
    const int rdst = bm * 64 + rl;       // unclamped dest row (dup tail data)

    f32x4 v[16];
    #pragma unroll
    for (int t = 0; t < 16; ++t) v[t] = *(const f32x4*)(src + t * 32);
    #pragma unroll
    for (int t = 0; t < 16; ++t) {
        bf16x4 o;
        o[0] = (__bf16)v[t][0]; o[1] = (__bf16)v[t][1];
        o[2] = (__bf16)v[t][2]; o[3] = (__bf16)v[t][3];
        *(bf16x4*)((char*)At + (size_t)t * AT_TSTRIDE + (size_t)rdst * 64 + oct * 8) = o;
    }
}

// ---------- K1: pure-register MFMA GEMM -> packed sign bits ----------
// Tile 64(M) x 512(N), 512 threads = 8 waves (wave = 64x64 col panel).
// NO LDS, NO barriers, NO cvt in the K-loop: both A and B fragments are
// direct global->reg bf16x8 loads from tile-major layouts where every
// fragment wave-load is 1KB fully contiguous. 3-buffer rotation, loads
// issued 2 tiles ahead; compiler-counted vmcnt waits.
__global__ void __launch_bounds__(512)
gemm_signs(const __bf16* __restrict__ At,
           const __bf16* __restrict__ Wt,
           uint64_t* __restrict__ sbits) {
    __shared__ unsigned char sb[512 * 68];   // epilogue only (34.8KB)

    const int tid    = threadIdx.x;
    const int lane   = tid & 63;
    const int wc     = tid >> 6;       // wave 0..7 = 64-col panel
    const int lane16 = lane & 15;
    const int lgrp   = lane >> 4;

    // bijective XCD swizzle: nwg=1564=8*195+4 (m204)
    const int orig = blockIdx.x;
    const int x    = orig & 7;
    const int bm   = (x < 4 ? x * 196 : 784 + (x - 4) * 195) + (orig >> 3);  // 0..1563

    const char* abase = (const char*)At;
    const char* wbase = (const char*)Wt;
    int afofs[4], bfofs[4];
    #pragma unroll
    for (int m = 0; m < 4; ++m)
        afofs[m] = (bm * 64 + m * 16 + lane16) * 64 + lgrp * 16;
    #pragma unroll
    for (int n = 0; n < 4; ++n)
        bfofs[n] = (wc * 64 + n * 16 + lane16) * 64 + lgrp * 16;

    f32x4  acc[4][4] = {};
    bf16x8 af[3][4], bf[3][4];         // 3-buffer, depth-2 prefetch

    #pragma unroll
    for (int u = 0; u < 2; ++u) {      // prologue: tiles 0,1 in flight
        #pragma unroll
        for (int m = 0; m < 4; ++m)
            af[u][m] = *(const bf16x8*)(abase + (size_t)u * AT_TSTRIDE + afofs[m]);
        #pragma unroll
        for (int n = 0; n < 4; ++n)
            bf[u][n] = *(const bf16x8*)(wbase + (size_t)u * 32768 + bfofs[n]);
    }

    #pragma unroll
    for (int t = 0; t < 16; ++t) {
        if (t < 14) {                  // issue t+2 into buffer (t+2)%3
            const int nb = (t + 2) % 3;
            #pragma unroll
            for (int m = 0; m < 4; ++m)
                af[nb][m] = *(const bf16x8*)(abase + (size_t)(t + 2) * AT_TSTRIDE + afofs[m]);
            #pragma unroll
            for (int n = 0; n < 4; ++n)
                bf[nb][n] = *(const bf16x8*)(wbase + (size_t)(t + 2) * 32768 + bfofs[n]);
        }
        const int cb = t % 3;          // consume tile t (vmcnt wait auto-inserted)
        __builtin_amdgcn_s_setprio(1);
        #pragma unroll
        for (int m = 0; m < 4; ++m)
            #pragma unroll
            for (int n = 0; n < 4; ++n)
                acc[m][n] = __builtin_amdgcn_mfma_f32_16x16x32_bf16(
                    af[cb][m], bf[cb][n], acc[m][n], 0, 0, 0);
        __builtin_amdgcn_s_setprio(0);
    }

    // ---- epilogue: sign bytes -> LDS transpose -> multiply-pack -> u64 ----
    // C/D layout: col = lane&15, row = (lane>>4)*4 + reg
    #pragma unroll
    for (int m = 0; m < 4; ++m) {
        #pragma unroll
        for (int n = 0; n < 4; ++n) {
            int cc = wc * 64 + n * 16 + lane16;   // col 0..511
            int rb = m * 16 + lgrp * 4;           // row base 0..60
            uint32_t pk = 0;
            #pragma unroll
            for (int rg = 0; rg < 4; ++rg)
                pk |= (acc[m][n][rg] < 0.0f ? 1u : 0u) << (8 * rg);
            *(uint32_t*)&sb[cc * 68 + rb] = pk;
        }
    }
    __syncthreads();

    {   // one thread per column; 64 sign bytes -> u64; word index = bm
        const unsigned char* src = &sb[tid * 68];
        uint64_t wbits = 0;
        #pragma unroll
        for (int k = 0; k < 16; ++k) {
            uint32_t qv = *(const uint32_t*)&src[4 * k];
            uint32_t p4 = ((qv & 0x01010101u) * 0x10204080u) >> 28;
            wbits |= (uint64_t)p4 << (4 * k);
        }
        sbits[(size_t)bm * 512 + tid] = wbits;    // 4KB contiguous per block
    }
}

// ---------- K2: crossing masks from sign bits ----------
__global__ void crossing_masks(const uint64_t* __restrict__ sbits,
                               uint64_t* __restrict__ maskT) {
    const int w = blockIdx.x;       // 0..1562
    const int j = threadIdx.x;      // 0..255
    uint64_t s0r = sbits[(size_t)w * 512 + j];
    uint64_t s0p = sbits[(size_t)w * 512 + 256 + j];
    uint64_t s1r = sbits[(size_t)(w + 1) * 512 + j];
    uint64_t s1p = sbits[(size_t)(w + 1) * 512 + 256 + j];
    uint64_t cr = s0r ^ ((s0r >> 1) | (s1r << 63));
    uint64_t cp = s0p ^ ((s0p >> 1) | (s1p << 63));
    uint64_t m = cr & cp;
    if (w == NW - 1) m &= 0x7FFFFFFFull;    // 31 valid crossings in last word
    maskT[(size_t)w * 256 + j] = m;
}

// ---------- K3: pairwise AND-popcount ----------
__global__ void zero_out(float* __restrict__ out) {
    int i = blockIdx.x * 256 + threadIdx.x;
    if (i < 32640) out[i] = 0.0f;
}

__global__ void pair_popcount(const uint64_t* __restrict__ maskT,
                              float* __restrict__ out) {
    const int i = blockIdx.x;   // 0..255
    const int c = blockIdx.y;   // 0..7 word chunk
    const int j = threadIdx.x;  // 0..255
    if (j <= i) return;
    int w0 = c * 196;
    int w1 = w0 + 196; if (w1 > NW) w1 = NW;
    uint32_t sum = 0;
    #pragma unroll 4
    for (int w = w0; w < w1; ++w) {
        uint64_t mi = maskT[(size_t)w * 256 + i];   // block-uniform -> scalar
        uint64_t mj = maskT[(size_t)w * 256 + j];   // coalesced
        sum += (uint32_t)__popcll(mi & mj);
    }
    const size_t idx = (size_t)i * (2 * KDIM - i - 1) / 2 + (size_t)(j - i - 1);
    atomicAdd(&out[idx], (float)sum);   // exact-integer f32 adds -> deterministic
}

extern "C" void kernel_launch(void* const* d_in, const int* in_sizes, int n_in,
                              void* d_out, int out_size, void* d_ws, size_t ws_size,
                              hipStream_t stream) {
    const float* theta = (const float*)d_in[0];
    const float* basis = (const float*)d_in[1];
    const float* noise = (const float*)d_in[2];
    float* out = (float*)d_out;

    char* ws = (char*)d_ws;
    __bf16*   Wt    = (__bf16*)ws;                      // 512 KB @ 0
    __bf16*   At    = (__bf16*)(ws + (1u << 20));       // 102.5 MB @ 1MB
    uint64_t* sbits = (uint64_t*)(ws + (110u << 20));   // 6.41 MB @ 110MB
    uint64_t* maskT = (uint64_t*)(ws + (118u << 20));   // 3.2 MB  @ 118MB

    hipLaunchKernelGGL(build_w,        dim3(1024),    dim3(256), 0, stream, theta, noise, Wt);
    hipLaunchKernelGGL(cast_a,         dim3(NWORDS),  dim3(512), 0, stream, basis, At);
    hipLaunchKernelGGL(gemm_signs,     dim3(NWORDS),  dim3(512), 0, stream, At, Wt, sbits);
    hipLaunchKernelGGL(crossing_masks, dim3(NW),      dim3(256), 0, stream, sbits, maskT);
    hipLaunchKernelGGL(zero_out,       dim3(128),     dim3(256), 0, stream, out);
    hipLaunchKernelGGL(pair_popcount,  dim3(KDIM, 8), dim3(256), 0, stream, maskT, out);
}